// Round 13
// baseline (3672.676 us; speedup 1.0000x reference)
//
#include <hip/hip_runtime.h>
#include <hip/hip_bf16.h>
#include <stdint.h>

// BinaryDiff: out = x @ (base + coeff*(2*mask-1))
// M=8192, K=4096, N=4096. fp32 in/out, bf16 MFMA compute.
// R13: occupancy lever. Single-buffered 256x256/BK=64 tile -> LDS 64 KiB ->
// 2 blocks/CU. Cross-block overlap (m114): one block's MFMA burst hides the
// other's LDS-read burst + stage latency. Loop per K-tile:
//   stage(t) -> vmcnt(0) -> BAR -> read 24 frags -> lgkm(0) -> 64 MFMA -> BAR.
// Same 16x16x32 MFMA, XOR-swizzle (conflict-free), XCD swizzle, setprio.

typedef short bf16x8_t __attribute__((ext_vector_type(8)));
typedef float f32x4_t __attribute__((ext_vector_type(4)));
typedef unsigned short u16x8_t __attribute__((ext_vector_type(8)));

#define GLD_LDS16(gptr, lptr)                                                        \
  __builtin_amdgcn_global_load_lds(                                                  \
      (const __attribute__((address_space(1))) void*)(gptr),                         \
      (__attribute__((address_space(3))) void*)(lptr), 16, 0, 0)

#define MFMA_BF16 __builtin_amdgcn_mfma_f32_16x16x32_bf16

// ---------------------------------------------------------------- prep: x -> bf16
__global__ __launch_bounds__(256) void cast_x_kernel(const float* __restrict__ x,
                                                     __hip_bfloat16* __restrict__ xb) {
  size_t i = ((size_t)blockIdx.x * 256 + threadIdx.x) * 8;
  f32x4_t v0 = *(const f32x4_t*)&x[i];
  f32x4_t v1 = *(const f32x4_t*)&x[i + 4];
  __hip_bfloat16 tmp[8];
#pragma unroll
  for (int j = 0; j < 4; ++j) tmp[j] = __float2bfloat16(v0[j]);
#pragma unroll
  for (int j = 0; j < 4; ++j) tmp[4 + j] = __float2bfloat16(v1[j]);
  *(u16x8_t*)&xb[i] = *(const u16x8_t*)tmp;
}

// ------------------------------------- prep: Wt[n][k] = bf16(base[k][n] +/- coeff)
__global__ __launch_bounds__(256) void make_wt_kernel(const float* __restrict__ base,
                                                      const int* __restrict__ mask,
                                                      const float* __restrict__ coeffp,
                                                      __hip_bfloat16* __restrict__ wt,
                                                      int K, int N) {
  __shared__ float tile[32][33];
  const float coeff = coeffp[0];
  const int n0 = blockIdx.x * 32, k0 = blockIdx.y * 32;
  const int tx = threadIdx.x & 31;
  const int ty = threadIdx.x >> 5;
#pragma unroll
  for (int j = 0; j < 4; ++j) {
    int k = k0 + ty + j * 8;
    size_t idx = (size_t)k * N + n0 + tx;
    float b = base[idx];
    int m = mask[idx];
    tile[ty + j * 8][tx] = b + (m ? coeff : -coeff);
  }
  __syncthreads();
#pragma unroll
  for (int j = 0; j < 4; ++j) {
    int n = n0 + ty + j * 8;
    wt[(size_t)n * K + k0 + tx] = __float2bfloat16(tile[tx][ty + j * 8]);
  }
}

// --------------------------------------- main GEMM: 256^2 single-buf, 2 blocks/CU
// A = xb[M][K], B = wt[N][K] (W^T), C = out[M][N] fp32.
__global__ __launch_bounds__(512, 4) void gemm256_kernel(const __hip_bfloat16* __restrict__ xb,
                                                         const __hip_bfloat16* __restrict__ wt,
                                                         float* __restrict__ out,
                                                         int M, int N, int K) {
  __shared__ __align__(16) __hip_bfloat16 As[256 * 64];  // 32 KiB
  __shared__ __align__(16) __hip_bfloat16 Bs[256 * 64];  // 32 KiB
  const int NT = K >> 6;  // K-tiles of 64

  // XCD-aware swizzle (nwg = 512, %8==0 -> simple bijective form)
  const int nwg = gridDim.x;
  int bid = blockIdx.x;
  int sw = bid;
  if ((nwg & 7) == 0) {
    int per = nwg >> 3;
    sw = (bid & 7) * per + (bid >> 3);
  }
  const int ntn = N >> 8;
  const int tm = sw / ntn, tn = sw - tm * ntn;
  const int m0 = tm << 8, n0 = tn << 8;

  const int tid = threadIdx.x;
  const int lane = tid & 63;
  const int wave = tid >> 6;  // 0..7
  const int wr = wave >> 2;   // 0..1  (M direction, 128 rows each)
  const int wc = wave & 3;    // 0..3  (N direction, 64 cols each)

  // ---- staging: linear LDS dest, pre-swizzled global source (rule #21) ----
  const int lrow = lane >> 3;                 // 0..7 (row within 8-row chunk)
  const int lcol = ((lane & 7) ^ lrow) << 3;  // source col (elems), 16B-slot swizzle
  uint32_t aOff[2][2], bOff[2][2];            // global element offsets (static idx only)
#pragma unroll
  for (int h = 0; h < 2; ++h)
#pragma unroll
    for (int j = 0; j < 2; ++j) {
      aOff[h][j] = (uint32_t)((m0 + h * 128 + wave * 16 + j * 8 + lrow) * K + lcol);
      bOff[h][j] = (uint32_t)((n0 + h * 128 + wave * 16 + j * 8 + lrow) * K + lcol);
    }

// one half-tile = 2 x global_load_lds per wave (8 waves x 2 x 1KiB = 16 KiB)
#define STAGE_A(h, j, tau)                                                       \
  GLD_LDS16(xb + (size_t)aOff[h][j] + (size_t)(tau) * 64,                        \
            (char*)As + ((h) * 16384 + wave * 2048 + (j) * 1024))
#define STAGE_B(h, j, tau)                                                       \
  GLD_LDS16(wt + (size_t)bOff[h][j] + (size_t)(tau) * 64,                        \
            (char*)Bs + ((h) * 16384 + wave * 2048 + (j) * 1024))

#define STAGE_TILE(tau)                                                          \
  do {                                                                           \
    STAGE_A(0, 0, tau); STAGE_A(0, 1, tau);                                      \
    STAGE_A(1, 0, tau); STAGE_A(1, 1, tau);                                      \
    STAGE_B(0, 0, tau); STAGE_B(0, 1, tau);                                      \
    STAGE_B(1, 0, tau); STAGE_B(1, 1, tau);                                      \
  } while (0)

  // ---- ds_read addressing: XOR-swizzled (row&7 == lane&7 on fragment rows) ----
  const int lane15 = lane & 15;
  const int swz = (lane & 7) << 4;
  const int c0 = (((lane >> 4) << 4)) ^ swz;      // ks=0 col byte (slots 0..3)
  const int c1 = (64 + ((lane >> 4) << 4)) ^ swz; // ks=1 col byte (slots 4..7)
  const char* a0 = (const char*)As + (wr * 128 + lane15) * 128;
  const char* b0 = (const char*)Bs + (wc * 64 + lane15) * 128;

  f32x4_t acc[8][4];
  const f32x4_t zero = {0.0f, 0.0f, 0.0f, 0.0f};
#pragma unroll
  for (int i = 0; i < 8; ++i)
#pragma unroll
    for (int j = 0; j < 4; ++j) acc[i][j] = zero;

  bf16x8_t aL[4][2], aH[4][2], bL[2][2], bH[2][2];

  for (int t = 0; t < NT; ++t) {
    // ---- stage tile t into the single buffer ----
    // WAR: previous tile's readers all retired (lgkm0) and passed the
    // end-of-tile barrier before this stage executes. SAFE.
    STAGE_TILE(t);
    asm volatile("s_waitcnt vmcnt(0)" ::: "memory");  // hidden by co-resident block
    __builtin_amdgcn_s_barrier();

    // ---- read all 24 fragments of tile t ----
#pragma unroll
    for (int mi = 0; mi < 4; ++mi) {
      aL[mi][0] = *(const bf16x8_t*)(a0 + mi * 2048 + c0);
      aL[mi][1] = *(const bf16x8_t*)(a0 + mi * 2048 + c1);
      aH[mi][0] = *(const bf16x8_t*)(a0 + (mi + 4) * 2048 + c0);
      aH[mi][1] = *(const bf16x8_t*)(a0 + (mi + 4) * 2048 + c1);
    }
#pragma unroll
    for (int ni = 0; ni < 2; ++ni) {
      bL[ni][0] = *(const bf16x8_t*)(b0 + ni * 2048 + c0);
      bL[ni][1] = *(const bf16x8_t*)(b0 + ni * 2048 + c1);
      bH[ni][0] = *(const bf16x8_t*)(b0 + (ni + 2) * 2048 + c0);
      bH[ni][1] = *(const bf16x8_t*)(b0 + (ni + 2) * 2048 + c1);
    }
    asm volatile("s_waitcnt lgkmcnt(0)" ::: "memory");
    __builtin_amdgcn_sched_barrier(0);
    __builtin_amdgcn_s_setprio(1);
#pragma unroll
    for (int mi = 0; mi < 4; ++mi)
#pragma unroll
      for (int ni = 0; ni < 2; ++ni) {
        acc[mi][ni] = MFMA_BF16(aL[mi][0], bL[ni][0], acc[mi][ni], 0, 0, 0);
        acc[mi][ni] = MFMA_BF16(aL[mi][1], bL[ni][1], acc[mi][ni], 0, 0, 0);
        acc[mi][ni + 2] = MFMA_BF16(aL[mi][0], bH[ni][0], acc[mi][ni + 2], 0, 0, 0);
        acc[mi][ni + 2] = MFMA_BF16(aL[mi][1], bH[ni][1], acc[mi][ni + 2], 0, 0, 0);
        acc[mi + 4][ni + 2] = MFMA_BF16(aH[mi][0], bH[ni][0], acc[mi + 4][ni + 2], 0, 0, 0);
        acc[mi + 4][ni + 2] = MFMA_BF16(aH[mi][1], bH[ni][1], acc[mi + 4][ni + 2], 0, 0, 0);
        acc[mi + 4][ni] = MFMA_BF16(aH[mi][0], bL[ni][0], acc[mi + 4][ni], 0, 0, 0);
        acc[mi + 4][ni] = MFMA_BF16(aH[mi][1], bL[ni][1], acc[mi + 4][ni], 0, 0, 0);
      }
    __builtin_amdgcn_s_setprio(0);
    __builtin_amdgcn_s_barrier();  // all reads of tile t done before next stage
  }

  // ---- epilogue: C/D layout col=lane&15, row=(lane>>4)*4+reg ----
  const int row0 = m0 + wr * 128 + (lane >> 4) * 4;
  const int col0 = n0 + wc * 64 + lane15;
#pragma unroll
  for (int mi = 0; mi < 8; ++mi)
#pragma unroll
    for (int ni = 0; ni < 4; ++ni) {
#pragma unroll
      for (int k = 0; k < 4; ++k)
        out[(size_t)(row0 + mi * 16 + k) * N + col0 + ni * 16] = acc[mi][ni][k];
    }
#undef STAGE_TILE
#undef STAGE_A
#undef STAGE_B
}

// ------------------------------------------- fallback (no workspace): fused GEMM
__global__ __launch_bounds__(256) void gemm_fallback_kernel(const float* __restrict__ x,
                                                            const float* __restrict__ base,
                                                            const int* __restrict__ mask,
                                                            const float* __restrict__ coeffp,
                                                            float* __restrict__ out,
                                                            int M, int N, int K) {
  __shared__ __align__(16) __hip_bfloat16 As[128 * 32];
  __shared__ __align__(16) __hip_bfloat16 Bs[128 * 32];
  const float coeff = coeffp[0];
  const int ntn = N >> 7;
  const int tm = blockIdx.x / ntn, tn = blockIdx.x - tm * ntn;
  const int m0 = tm << 7, n0 = tn << 7;
  const int tid = threadIdx.x, lane = tid & 63, wave = tid >> 6;
  const int wr = wave >> 1, wc = wave & 1;

  f32x4_t acc[4][4];
  const f32x4_t zero = {0.0f, 0.0f, 0.0f, 0.0f};
#pragma unroll
  for (int i = 0; i < 4; ++i)
#pragma unroll
    for (int j = 0; j < 4; ++j) acc[i][j] = zero;

  const int arow = tid >> 1;
  const int acol = (tid & 1) * 16;
  const int bkk = tid & 31;
  const int bnb = (tid >> 5) * 16;
  const int arow_base = wr * 64 + (lane & 15);
  const int bcol_base = wc * 64 + (lane & 15);
  const int koff = (lane >> 4) * 8;

  for (int k0 = 0; k0 < K; k0 += 32) {
    __syncthreads();
    {
      const float* src = &x[(size_t)(m0 + arow) * K + k0 + acol];
      __hip_bfloat16 tmp[16];
#pragma unroll
      for (int j = 0; j < 16; ++j) tmp[j] = __float2bfloat16(src[j]);
      *(u16x8_t*)&As[arow * 32 + acol] = *(const u16x8_t*)&tmp[0];
      *(u16x8_t*)&As[arow * 32 + acol + 8] = *(const u16x8_t*)&tmp[8];
    }
    {
      const float* bsrc = &base[(size_t)(k0 + bkk) * N + n0 + bnb];
      const int* msrc = &mask[(size_t)(k0 + bkk) * N + n0 + bnb];
#pragma unroll
      for (int j = 0; j < 16; ++j) {
        float w = bsrc[j] + (msrc[j] ? coeff : -coeff);
        Bs[(bnb + j) * 32 + bkk] = __float2bfloat16(w);
      }
    }
    __syncthreads();

    bf16x8_t a[4], b[4];
#pragma unroll
    for (int mi = 0; mi < 4; ++mi)
      a[mi] = *(const bf16x8_t*)&As[(arow_base + mi * 16) * 32 + koff];
#pragma unroll
    for (int ni = 0; ni < 4; ++ni)
      b[ni] = *(const bf16x8_t*)&Bs[(bcol_base + ni * 16) * 32 + koff];
#pragma unroll
    for (int mi = 0; mi < 4; ++mi)
#pragma unroll
      for (int ni = 0; ni < 4; ++ni)
        acc[mi][ni] = MFMA_BF16(a[mi], b[ni], acc[mi][ni], 0, 0, 0);
  }

  const int row0 = m0 + wr * 64 + (lane >> 4) * 4;
  const int col0 = n0 + wc * 64 + (lane & 15);
#pragma unroll
  for (int mi = 0; mi < 4; ++mi)
#pragma unroll
    for (int ni = 0; ni < 4; ++ni) {
      int r = row0 + mi * 16;
      int c = col0 + ni * 16;
#pragma unroll
      for (int k = 0; k < 4; ++k) out[(size_t)(r + k) * N + c] = acc[mi][ni][k];
    }
}

// --------------------------------------------------------------------- launcher
extern "C" void kernel_launch(void* const* d_in, const int* in_sizes, int n_in,
                              void* d_out, int out_size, void* d_ws, size_t ws_size,
                              hipStream_t stream) {
  const int B = 4, S = 2048, DIN = 4096, DOUT = 4096;
  const int M = B * S;  // 8192
  const float* x = (const float*)d_in[0];
  const float* base = (const float*)d_in[1];
  const int* mask = (const int*)d_in[2];
  const float* coeff = (const float*)d_in[3];
  float* out = (float*)d_out;

  const size_t xb_bytes = (size_t)M * DIN * sizeof(__hip_bfloat16);
  const size_t wt_bytes = (size_t)DIN * DOUT * sizeof(__hip_bfloat16);

  if (ws_size >= xb_bytes + wt_bytes) {
    __hip_bfloat16* xb = (__hip_bfloat16*)d_ws;
    __hip_bfloat16* wt = (__hip_bfloat16*)((char*)d_ws + xb_bytes);
    cast_x_kernel<<<(M * DIN) / (256 * 8), 256, 0, stream>>>(x, xb);
    make_wt_kernel<<<dim3(DOUT / 32, DIN / 32), 256, 0, stream>>>(base, mask, coeff, wt, DIN, DOUT);
    const int n_tiles = (M / 256) * (DOUT / 256);  // 512
    gemm256_kernel<<<n_tiles, 512, 0, stream>>>(xb, wt, out, M, DOUT, DIN);
  } else {
    const int n_tiles = (M / 128) * (DOUT / 128);
    gemm_fallback_kernel<<<n_tiles, 256, 0, stream>>>(x, base, mask, coeff, out, M, DOUT, DIN);
  }
}

// Round 15
// 304.738 us; speedup vs baseline: 12.0519x; 12.0519x over previous
//
#include <hip/hip_runtime.h>
#include <hip/hip_bf16.h>
#include <stdint.h>

// BinaryDiff: out = x @ (base + coeff*(2*mask-1))
// M=8192, K=4096, N=4096. fp32 in/out, bf16 MFMA compute.
// R15 = R11 exactly (verified best: 249us GEMM / 305us total).
// 2-phase/K-tile, 16x16x32 MFMA, XOR-swizzled LDS (0 conflicts), 2 barriers
// per K-tile, stage slots P0:{A1,B0,B1}(t+1) P1:{A0}(t+2) issued AFTER the
// phase's ds_reads (ordering is load-bearing: R14's hoist raced a same-buffer
// stage against same-phase reads), counted vmcnt(2) at P1-end only.

typedef short bf16x8_t __attribute__((ext_vector_type(8)));
typedef float f32x4_t __attribute__((ext_vector_type(4)));
typedef unsigned short u16x8_t __attribute__((ext_vector_type(8)));

#define GLD_LDS16(gptr, lptr)                                                        \
  __builtin_amdgcn_global_load_lds(                                                  \
      (const __attribute__((address_space(1))) void*)(gptr),                         \
      (__attribute__((address_space(3))) void*)(lptr), 16, 0, 0)

#define MFMA_BF16 __builtin_amdgcn_mfma_f32_16x16x32_bf16

// ---------------------------------------------------------------- prep: x -> bf16
__global__ __launch_bounds__(256) void cast_x_kernel(const float* __restrict__ x,
                                                     __hip_bfloat16* __restrict__ xb) {
  size_t i = ((size_t)blockIdx.x * 256 + threadIdx.x) * 8;
  f32x4_t v0 = *(const f32x4_t*)&x[i];
  f32x4_t v1 = *(const f32x4_t*)&x[i + 4];
  __hip_bfloat16 tmp[8];
#pragma unroll
  for (int j = 0; j < 4; ++j) tmp[j] = __float2bfloat16(v0[j]);
#pragma unroll
  for (int j = 0; j < 4; ++j) tmp[4 + j] = __float2bfloat16(v1[j]);
  *(u16x8_t*)&xb[i] = *(const u16x8_t*)tmp;
}

// ------------------------------------- prep: Wt[n][k] = bf16(base[k][n] +/- coeff)
__global__ __launch_bounds__(256) void make_wt_kernel(const float* __restrict__ base,
                                                      const int* __restrict__ mask,
                                                      const float* __restrict__ coeffp,
                                                      __hip_bfloat16* __restrict__ wt,
                                                      int K, int N) {
  __shared__ float tile[32][33];
  const float coeff = coeffp[0];
  const int n0 = blockIdx.x * 32, k0 = blockIdx.y * 32;
  const int tx = threadIdx.x & 31;
  const int ty = threadIdx.x >> 5;
#pragma unroll
  for (int j = 0; j < 4; ++j) {
    int k = k0 + ty + j * 8;
    size_t idx = (size_t)k * N + n0 + tx;
    float b = base[idx];
    int m = mask[idx];
    tile[ty + j * 8][tx] = b + (m ? coeff : -coeff);
  }
  __syncthreads();
#pragma unroll
  for (int j = 0; j < 4; ++j) {
    int n = n0 + ty + j * 8;
    wt[(size_t)n * K + k0 + tx] = __float2bfloat16(tile[tx][ty + j * 8]);
  }
}

// ------------------------------------------------- main GEMM: 256^2, 2-phase/K-tile
// A = xb[M][K], B = wt[N][K] (W^T), C = out[M][N] fp32.
__global__ __launch_bounds__(512, 2) void gemm256_kernel(const __hip_bfloat16* __restrict__ xb,
                                                         const __hip_bfloat16* __restrict__ wt,
                                                         float* __restrict__ out,
                                                         int M, int N, int K) {
  __shared__ __align__(16) __hip_bfloat16 As[2 * 256 * 64];  // 64 KiB (2 x 32 KiB)
  __shared__ __align__(16) __hip_bfloat16 Bs[2 * 256 * 64];  // 64 KiB (2 x 32 KiB)
  const int NT = K >> 6;  // K-tiles of 64

  // XCD-aware swizzle (nwg = 512, %8==0 -> simple bijective form)
  const int nwg = gridDim.x;
  int bid = blockIdx.x;
  int sw = bid;
  if ((nwg & 7) == 0) {
    int per = nwg >> 3;
    sw = (bid & 7) * per + (bid >> 3);
  }
  const int ntn = N >> 8;
  const int tm = sw / ntn, tn = sw - tm * ntn;
  const int m0 = tm << 8, n0 = tn << 8;

  const int tid = threadIdx.x;
  const int lane = tid & 63;
  const int wave = tid >> 6;  // 0..7
  const int wr = wave >> 2;   // 0..1  (M direction, 128 rows each)
  const int wc = wave & 3;    // 0..3  (N direction, 64 cols each)

  // ---- staging: linear LDS dest, pre-swizzled global source (rule #21) ----
  const int lrow = lane >> 3;                 // 0..7 (row within 8-row chunk)
  const int lcol = ((lane & 7) ^ lrow) << 3;  // source col (elems), 16B-slot swizzle
  uint32_t aOff[2][2], bOff[2][2];            // global element offsets (static idx only)
#pragma unroll
  for (int h = 0; h < 2; ++h)
#pragma unroll
    for (int j = 0; j < 2; ++j) {
      aOff[h][j] = (uint32_t)((m0 + h * 128 + wave * 16 + j * 8 + lrow) * K + lcol);
      bOff[h][j] = (uint32_t)((n0 + h * 128 + wave * 16 + j * 8 + lrow) * K + lcol);
    }

// one half-tile = 2 x global_load_lds per wave (8 waves x 2 x 1KiB = 16 KiB)
// buffer half = 256 rows * 128 B = 32768 B -> (tau&1)<<15
#define STAGE_A(h, j, tau)                                                       \
  GLD_LDS16(xb + (size_t)aOff[h][j] + (size_t)(tau) * 64,                        \
            (char*)As + (((tau) & 1) << 15) + ((h) * 16384 + wave * 2048 + (j) * 1024))
#define STAGE_B(h, j, tau)                                                       \
  GLD_LDS16(wt + (size_t)bOff[h][j] + (size_t)(tau) * 64,                        \
            (char*)Bs + (((tau) & 1) << 15) + ((h) * 16384 + wave * 2048 + (j) * 1024))

  // ---- prologue: tile0 all 4 halves + tile1 A0 = 5 halves (10 loads) ----
  STAGE_A(0, 0, 0); STAGE_A(0, 1, 0);
  STAGE_A(1, 0, 0); STAGE_A(1, 1, 0);
  STAGE_B(0, 0, 0); STAGE_B(0, 1, 0);
  STAGE_B(1, 0, 0); STAGE_B(1, 1, 0);
  STAGE_A(0, 0, 1); STAGE_A(0, 1, 1);
  asm volatile("s_waitcnt vmcnt(2)" ::: "memory");  // tile0's 8 loads landed
  __builtin_amdgcn_s_barrier();

  // ---- ds_read addressing: XOR-swizzled (row&7 == lane&7 on fragment rows) ----
  const int lane15 = lane & 15;
  const int swz = (lane & 7) << 4;
  const int c0 = (((lane >> 4) << 4)) ^ swz;      // ks=0 col byte (slots 0..3)
  const int c1 = (64 + ((lane >> 4) << 4)) ^ swz; // ks=1 col byte (slots 4..7)
  const int aRowB = (wr * 128 + lane15) * 128;    // byte row base within buffer
  const int bRowB = (wc * 64 + lane15) * 128;

  f32x4_t acc[8][4];
  const f32x4_t zero = {0.0f, 0.0f, 0.0f, 0.0f};
#pragma unroll
  for (int i = 0; i < 8; ++i)
#pragma unroll
    for (int j = 0; j < 4; ++j) acc[i][j] = zero;

  bf16x8_t aL[4][2], aH[4][2], bL[2][2], bH[2][2];

  for (int t = 0; t < NT; ++t) {
    const int p = t & 1;
    const char* a0 = (const char*)As + (p << 15) + aRowB;
    const char* b0 = (const char*)Bs + (p << 15) + bRowB;

    // ===== Phase 0: read aL(8)+bL(4)+bH(4); stage A1,B0,B1(t+1);
    //       lgkm0; MFMA Q0+Q1; BAR =====
    // WAR: A1(t+1)->buf p^1 A1: reader aH(t-1) retired at P1(t-1) lgkm0,
    //   before BAR(P1(t-1)) which precedes this stage. SAFE.
    //   B0,B1(t+1)->buf p^1 B: readers bL,bH(t-1) retired at P0(t-1) lgkm0. SAFE.
    // RAW: buf p contents guarded by vmcnt@P1(t-1)-end + BAR. SAFE.
    // ORDER: reads issued BEFORE stages (R14 lesson — keeps every wave's
    //   ds_reads in the LDS queue before any stage DMA can land).
#pragma unroll
    for (int mi = 0; mi < 4; ++mi) {
      aL[mi][0] = *(const bf16x8_t*)(a0 + mi * 2048 + c0);
      aL[mi][1] = *(const bf16x8_t*)(a0 + mi * 2048 + c1);
    }
#pragma unroll
    for (int ni = 0; ni < 2; ++ni) {
      bL[ni][0] = *(const bf16x8_t*)(b0 + ni * 2048 + c0);
      bL[ni][1] = *(const bf16x8_t*)(b0 + ni * 2048 + c1);
      bH[ni][0] = *(const bf16x8_t*)(b0 + (ni + 2) * 2048 + c0);
      bH[ni][1] = *(const bf16x8_t*)(b0 + (ni + 2) * 2048 + c1);
    }
    if (t + 1 < NT) {
      STAGE_A(1, 0, t + 1); STAGE_A(1, 1, t + 1);
      STAGE_B(0, 0, t + 1); STAGE_B(0, 1, t + 1);
      STAGE_B(1, 0, t + 1); STAGE_B(1, 1, t + 1);
    }
    asm volatile("s_waitcnt lgkmcnt(0)" ::: "memory");
    __builtin_amdgcn_sched_barrier(0);
    __builtin_amdgcn_s_setprio(1);
#pragma unroll
    for (int mi = 0; mi < 4; ++mi)
#pragma unroll
      for (int ni = 0; ni < 2; ++ni) {
        acc[mi][ni] = MFMA_BF16(aL[mi][0], bL[ni][0], acc[mi][ni], 0, 0, 0);
        acc[mi][ni] = MFMA_BF16(aL[mi][1], bL[ni][1], acc[mi][ni], 0, 0, 0);
        acc[mi][ni + 2] = MFMA_BF16(aL[mi][0], bH[ni][0], acc[mi][ni + 2], 0, 0, 0);
        acc[mi][ni + 2] = MFMA_BF16(aL[mi][1], bH[ni][1], acc[mi][ni + 2], 0, 0, 0);
      }
    __builtin_amdgcn_s_setprio(0);
    __builtin_amdgcn_s_barrier();

    // ===== Phase 1: read aH(8); stage A0(t+2); lgkm0; MFMA Q2+Q3;
    //       vmcnt(2) (all of t+1 resident); BAR =====
    // WAR: A0(t+2)->buf p A0: reader aL(t) retired at P0(t) lgkm0, before
    //   BAR(P0(t)) which precedes this stage; same-phase aH reads are issued
    //   BEFORE the stage (ordering load-bearing, see R14). SAFE.
#pragma unroll
    for (int mi = 0; mi < 4; ++mi) {
      aH[mi][0] = *(const bf16x8_t*)(a0 + (mi + 4) * 2048 + c0);
      aH[mi][1] = *(const bf16x8_t*)(a0 + (mi + 4) * 2048 + c1);
    }
    if (t + 2 < NT) { STAGE_A(0, 0, t + 2); STAGE_A(0, 1, t + 2); }
    asm volatile("s_waitcnt lgkmcnt(0)" ::: "memory");
    __builtin_amdgcn_sched_barrier(0);
    __builtin_amdgcn_s_setprio(1);
#pragma unroll
    for (int mi = 0; mi < 4; ++mi)
#pragma unroll
      for (int ni = 0; ni < 2; ++ni) {
        acc[mi + 4][ni + 2] = MFMA_BF16(aH[mi][0], bH[ni][0], acc[mi + 4][ni + 2], 0, 0, 0);
        acc[mi + 4][ni + 2] = MFMA_BF16(aH[mi][1], bH[ni][1], acc[mi + 4][ni + 2], 0, 0, 0);
        acc[mi + 4][ni] = MFMA_BF16(aH[mi][0], bL[ni][0], acc[mi + 4][ni], 0, 0, 0);
        acc[mi + 4][ni] = MFMA_BF16(aH[mi][1], bL[ni][1], acc[mi + 4][ni], 0, 0, 0);
      }
    __builtin_amdgcn_s_setprio(0);
    // vmcnt ledger at P1(t)-end (steady): {P1(t-1):2 [A0(t+1)], P0(t):6
    // [A1,B0,B1(t+1)], P1(t):2 [A0(t+2)]}. vmcnt(2) retires everything of
    // t+1. Tail: t=NT-2 -> P1 staged 0 -> vmcnt(0); t=NT-1 -> none needed.
    if (t + 2 < NT)      asm volatile("s_waitcnt vmcnt(2)" ::: "memory");
    else if (t + 1 < NT) asm volatile("s_waitcnt vmcnt(0)" ::: "memory");
    __builtin_amdgcn_s_barrier();
  }

  // ---- epilogue: C/D layout col=lane&15, row=(lane>>4)*4+reg ----
  const int row0 = m0 + wr * 128 + (lane >> 4) * 4;
  const int col0 = n0 + wc * 64 + lane15;
#pragma unroll
  for (int mi = 0; mi < 8; ++mi)
#pragma unroll
    for (int ni = 0; ni < 4; ++ni) {
#pragma unroll
      for (int k = 0; k < 4; ++k)
        out[(size_t)(row0 + mi * 16 + k) * N + col0 + ni * 16] = acc[mi][ni][k];
    }
#undef STAGE_A
#undef STAGE_B
}

// ------------------------------------------- fallback (no workspace): fused GEMM
__global__ __launch_bounds__(256) void gemm_fallback_kernel(const float* __restrict__ x,
                                                            const float* __restrict__ base,
                                                            const int* __restrict__ mask,
                                                            const float* __restrict__ coeffp,
                                                            float* __restrict__ out,
                                                            int M, int N, int K) {
  __shared__ __align__(16) __hip_bfloat16 As[128 * 32];
  __shared__ __align__(16) __hip_bfloat16 Bs[128 * 32];
  const float coeff = coeffp[0];
  const int ntn = N >> 7;
  const int tm = blockIdx.x / ntn, tn = blockIdx.x - tm * ntn;
  const int m0 = tm << 7, n0 = tn << 7;
  const int tid = threadIdx.x, lane = tid & 63, wave = tid >> 6;
  const int wr = wave >> 1, wc = wave & 1;

  f32x4_t acc[4][4];
  const f32x4_t zero = {0.0f, 0.0f, 0.0f, 0.0f};
#pragma unroll
  for (int i = 0; i < 4; ++i)
#pragma unroll
    for (int j = 0; j < 4; ++j) acc[i][j] = zero;

  const int arow = tid >> 1;
  const int acol = (tid & 1) * 16;
  const int bkk = tid & 31;
  const int bnb = (tid >> 5) * 16;
  const int arow_base = wr * 64 + (lane & 15);
  const int bcol_base = wc * 64 + (lane & 15);
  const int koff = (lane >> 4) * 8;

  for (int k0 = 0; k0 < K; k0 += 32) {
    __syncthreads();
    {
      const float* src = &x[(size_t)(m0 + arow) * K + k0 + acol];
      __hip_bfloat16 tmp[16];
#pragma unroll
      for (int j = 0; j < 16; ++j) tmp[j] = __float2bfloat16(src[j]);
      *(u16x8_t*)&As[arow * 32 + acol] = *(const u16x8_t*)&tmp[0];
      *(u16x8_t*)&As[arow * 32 + acol + 8] = *(const u16x8_t*)&tmp[8];
    }
    {
      const float* bsrc = &base[(size_t)(k0 + bkk) * N + n0 + bnb];
      const int* msrc = &mask[(size_t)(k0 + bkk) * N + n0 + bnb];
#pragma unroll
      for (int j = 0; j < 16; ++j) {
        float w = bsrc[j] + (msrc[j] ? coeff : -coeff);
        Bs[(bnb + j) * 32 + bkk] = __float2bfloat16(w);
      }
    }
    __syncthreads();

    bf16x8_t a[4], b[4];
#pragma unroll
    for (int mi = 0; mi < 4; ++mi)
      a[mi] = *(const bf16x8_t*)&As[(arow_base + mi * 16) * 32 + koff];
#pragma unroll
    for (int ni = 0; ni < 4; ++ni)
      b[ni] = *(const bf16x8_t*)&Bs[(bcol_base + ni * 16) * 32 + koff];
#pragma unroll
    for (int mi = 0; mi < 4; ++mi)
#pragma unroll
      for (int ni = 0; ni < 4; ++ni)
        acc[mi][ni] = MFMA_BF16(a[mi], b[ni], acc[mi][ni], 0, 0, 0);
  }

  const int row0 = m0 + wr * 64 + (lane >> 4) * 4;
  const int col0 = n0 + wc * 64 + (lane & 15);
#pragma unroll
  for (int mi = 0; mi < 4; ++mi)
#pragma unroll
    for (int ni = 0; ni < 4; ++ni) {
      int r = row0 + mi * 16;
      int c = col0 + ni * 16;
#pragma unroll
      for (int k = 0; k < 4; ++k) out[(size_t)(r + k) * N + c] = acc[mi][ni][k];
    }
}

// --------------------------------------------------------------------- launcher
extern "C" void kernel_launch(void* const* d_in, const int* in_sizes, int n_in,
                              void* d_out, int out_size, void* d_ws, size_t ws_size,
                              hipStream_t stream) {
  const int B = 4, S = 2048, DIN = 4096, DOUT = 4096;
  const int M = B * S;  // 8192
  const float* x = (const float*)d_in[0];
  const float* base = (const float*)d_in[1];
  const int* mask = (const int*)d_in[2];
  const float* coeff = (const float*)d_in[3];
  float* out = (float*)d_out;

  const size_t xb_bytes = (size_t)M * DIN * sizeof(__hip_bfloat16);
  const size_t wt_bytes = (size_t)DIN * DOUT * sizeof(__hip_bfloat16);

  if (ws_size >= xb_bytes + wt_bytes) {
    __hip_bfloat16* xb = (__hip_bfloat16*)d_ws;
    __hip_bfloat16* wt = (__hip_bfloat16*)((char*)d_ws + xb_bytes);
    cast_x_kernel<<<(M * DIN) / (256 * 8), 256, 0, stream>>>(x, xb);
    make_wt_kernel<<<dim3(DOUT / 32, DIN / 32), 256, 0, stream>>>(base, mask, coeff, wt, DIN, DOUT);
    const int n_tiles = (M / 256) * (DOUT / 256);  // 512
    gemm256_kernel<<<n_tiles, 512, 0, stream>>>(xb, wt, out, M, DOUT, DIN);
  } else {
    const int n_tiles = (M / 128) * (DOUT / 128);
    gemm_fallback_kernel<<<n_tiles, 256, 0, stream>>>(x, base, mask, coeff, out, M, DOUT, DIN);
  }
}